// Round 1
// baseline (1596.875 us; speedup 1.0000x reference)
//
#include <hip/hip_runtime.h>

// GCNConv forward: out = segment_sum(vals * (x@W)[cols], rows) + bias
// Inputs: x[N,256] f32, edge_rows[E] i32, edge_cols[E] i32, edge_vals[E] f32,
//         weight[256,128] f32, bias[128] f32.  Output: [N,128] f32.
// d_ws holds h = x@W  (N*128*4 = 51.2 MB).

#define NODES_PER_BLOCK 32

// ---------------- GEMM: h = x @ W ----------------
// Block: 256 threads, 32 rows. LDS: W k-tile [64][128] (32KB) + x tile
// transposed [64 c][36 pad] (9KB). Thread (fp = t&63, rg = t>>6) computes
// rows rg*8..rg*8+7, features 2*fp, 2*fp+1.
__global__ __launch_bounds__(256) void gemm_xw(const float* __restrict__ x,
                                               const float* __restrict__ w,
                                               float* __restrict__ h,
                                               int n_nodes) {
  __shared__ float wt[64 * 128];   // wt[c*128 + f] = W[k0+c][f]
  __shared__ float xt[64 * 36];    // xt[c*36 + r] = x[row0+r][k0+c]  (pad 36: 8-way wr conflict, aligned b128 rd)
  const int t = threadIdx.x;
  const int fp = t & 63;
  const int rg = t >> 6;
  const int row0 = blockIdx.x * NODES_PER_BLOCK;

  float acc[8][2];
#pragma unroll
  for (int r = 0; r < 8; ++r) { acc[r][0] = 0.f; acc[r][1] = 0.f; }

  for (int kt = 0; kt < 4; ++kt) {
    const int k0 = kt * 64;
    // W tile: 8192 floats = 2048 float4, 8 per thread, coalesced.
    const float4* wg = (const float4*)(w + k0 * 128);
    float4* wl = (float4*)wt;
#pragma unroll
    for (int i = 0; i < 8; ++i) wl[i * 256 + t] = wg[i * 256 + t];
    // x tile: 32 rows x 64 k, transposed into LDS. Lane-consecutive c => coalesced global.
#pragma unroll
    for (int i = 0; i < 8; ++i) {
      int idx = i * 256 + t;
      int r = idx >> 6, c = idx & 63;
      int row = row0 + r;
      xt[c * 36 + r] = (row < n_nodes) ? x[(size_t)row * 256 + k0 + c] : 0.f;
    }
    __syncthreads();
#pragma unroll 4
    for (int c = 0; c < 64; ++c) {
      const float2 wv = *(const float2*)&wt[c * 128 + fp * 2];          // 2-way alias: free
      const float4 xa = *(const float4*)&xt[c * 36 + rg * 8];           // wave-broadcast
      const float4 xb = *(const float4*)&xt[c * 36 + rg * 8 + 4];       // wave-broadcast
      acc[0][0] += xa.x * wv.x; acc[0][1] += xa.x * wv.y;
      acc[1][0] += xa.y * wv.x; acc[1][1] += xa.y * wv.y;
      acc[2][0] += xa.z * wv.x; acc[2][1] += xa.z * wv.y;
      acc[3][0] += xa.w * wv.x; acc[3][1] += xa.w * wv.y;
      acc[4][0] += xb.x * wv.x; acc[4][1] += xb.x * wv.y;
      acc[5][0] += xb.y * wv.x; acc[5][1] += xb.y * wv.y;
      acc[6][0] += xb.z * wv.x; acc[6][1] += xb.z * wv.y;
      acc[7][0] += xb.w * wv.x; acc[7][1] += xb.w * wv.y;
    }
    __syncthreads();
  }
#pragma unroll
  for (int r = 0; r < 8; ++r) {
    int row = row0 + rg * 8 + r;
    if (row < n_nodes) {
      float2 o; o.x = acc[r][0]; o.y = acc[r][1];
      *(float2*)&h[(size_t)row * 128 + fp * 2] = o;
    }
  }
}

// ---------------- out = bias (broadcast) ----------------
__global__ __launch_bounds__(256) void init_bias(float* __restrict__ out,
                                                 const float* __restrict__ bias,
                                                 int n4) {
  int i = blockIdx.x * 256 + threadIdx.x;
  if (i < n4) {
    float4 b = ((const float4*)bias)[i & 31];  // 128 floats = 32 float4 per row
    ((float4*)out)[i] = b;
  }
}

// ---------------- edge scatter: out[row] += val * h[col] ----------------
// One wave per edge; lane l handles features 2l, 2l+1.
__global__ __launch_bounds__(256) void scatter_edges(
    const float* __restrict__ h, const int* __restrict__ erows,
    const int* __restrict__ ecols, const float* __restrict__ evals,
    float* __restrict__ out, int n_edges) {
  int e = blockIdx.x * 4 + (threadIdx.x >> 6);
  if (e >= n_edges) return;
  int lane = threadIdx.x & 63;
  int row = erows[e];          // wave-uniform broadcast load
  int col = ecols[e];
  float v = evals[e];
  float2 m = ((const float2*)(h + (size_t)col * 128))[lane];  // coalesced 512B
  float* op = out + (size_t)row * 128 + lane * 2;
  atomicAdd(op, v * m.x);
  atomicAdd(op + 1, v * m.y);
}

extern "C" void kernel_launch(void* const* d_in, const int* in_sizes, int n_in,
                              void* d_out, int out_size, void* d_ws, size_t ws_size,
                              hipStream_t stream) {
  const float* x     = (const float*)d_in[0];
  const int*   erows = (const int*)d_in[1];
  const int*   ecols = (const int*)d_in[2];
  const float* evals = (const float*)d_in[3];
  const float* w     = (const float*)d_in[4];
  const float* bias  = (const float*)d_in[5];
  float* out = (float*)d_out;
  float* h   = (float*)d_ws;

  const int n_nodes = in_sizes[0] / 256;
  const int n_edges = in_sizes[1];

  const int gemm_blocks = (n_nodes + NODES_PER_BLOCK - 1) / NODES_PER_BLOCK;
  gemm_xw<<<gemm_blocks, 256, 0, stream>>>(x, w, h, n_nodes);

  const int n4 = out_size / 4;
  init_bias<<<(n4 + 255) / 256, 256, 0, stream>>>(out, bias, n4);

  scatter_edges<<<(n_edges + 3) / 4, 256, 0, stream>>>(h, erows, ecols, evals,
                                                       out, n_edges);
}

// Round 2
// 854.275 us; speedup vs baseline: 1.8693x; 1.8693x over previous
//
#include <hip/hip_runtime.h>

// GCNConv forward: out = segment_sum(vals * (x@W)[cols], rows) + bias
// Round 2: replace 204.8M-atomic scatter with on-device CSR build + per-node
// gather (no atomics on the 51 MB output).
//
// ws layout: h[N*128] f32 | counts[N] i32 | offsets[N+1] i32 | cursor[N] i32 |
//            sedge[E] int2 (col, val-bits)

#define NODES_PER_BLOCK 32

// ---------------- GEMM: h = x @ W ----------------
__global__ __launch_bounds__(256) void gemm_xw(const float* __restrict__ x,
                                               const float* __restrict__ w,
                                               float* __restrict__ h,
                                               int n_nodes) {
  __shared__ float wt[64 * 128];   // wt[c*128 + f] = W[k0+c][f]
  __shared__ float xt[64 * 36];    // xt[c*36 + r] = x[row0+r][k0+c]
  const int t = threadIdx.x;
  const int fp = t & 63;
  const int rg = t >> 6;
  const int row0 = blockIdx.x * NODES_PER_BLOCK;

  float acc[8][2];
#pragma unroll
  for (int r = 0; r < 8; ++r) { acc[r][0] = 0.f; acc[r][1] = 0.f; }

  for (int kt = 0; kt < 4; ++kt) {
    const int k0 = kt * 64;
    const float4* wg = (const float4*)(w + k0 * 128);
    float4* wl = (float4*)wt;
#pragma unroll
    for (int i = 0; i < 8; ++i) wl[i * 256 + t] = wg[i * 256 + t];
#pragma unroll
    for (int i = 0; i < 8; ++i) {
      int idx = i * 256 + t;
      int r = idx >> 6, c = idx & 63;
      int row = row0 + r;
      xt[c * 36 + r] = (row < n_nodes) ? x[(size_t)row * 256 + k0 + c] : 0.f;
    }
    __syncthreads();
#pragma unroll 4
    for (int c = 0; c < 64; ++c) {
      const float2 wv = *(const float2*)&wt[c * 128 + fp * 2];
      const float4 xa = *(const float4*)&xt[c * 36 + rg * 8];
      const float4 xb = *(const float4*)&xt[c * 36 + rg * 8 + 4];
      acc[0][0] += xa.x * wv.x; acc[0][1] += xa.x * wv.y;
      acc[1][0] += xa.y * wv.x; acc[1][1] += xa.y * wv.y;
      acc[2][0] += xa.z * wv.x; acc[2][1] += xa.z * wv.y;
      acc[3][0] += xa.w * wv.x; acc[3][1] += xa.w * wv.y;
      acc[4][0] += xb.x * wv.x; acc[4][1] += xb.x * wv.y;
      acc[5][0] += xb.y * wv.x; acc[5][1] += xb.y * wv.y;
      acc[6][0] += xb.z * wv.x; acc[6][1] += xb.z * wv.y;
      acc[7][0] += xb.w * wv.x; acc[7][1] += xb.w * wv.y;
    }
    __syncthreads();
  }
#pragma unroll
  for (int r = 0; r < 8; ++r) {
    int row = row0 + rg * 8 + r;
    if (row < n_nodes) {
      float2 o; o.x = acc[r][0]; o.y = acc[r][1];
      *(float2*)&h[(size_t)row * 128 + fp * 2] = o;
    }
  }
}

// ---------------- CSR build ----------------
__global__ __launch_bounds__(256) void hist_rows(const int* __restrict__ erows,
                                                 int* __restrict__ counts,
                                                 int n_edges) {
  int i = blockIdx.x * 256 + threadIdx.x;
  if (i < n_edges) atomicAdd(&counts[erows[i]], 1);
}

// Single block, 1024 threads: exclusive scan of counts[0..n) -> offsets, cursor.
__global__ __launch_bounds__(1024) void scan_counts(const int* __restrict__ counts,
                                                    int* __restrict__ offsets,
                                                    int* __restrict__ cursor,
                                                    int n) {
  __shared__ int sums[1024];
  const int t = threadIdx.x;
  const int chunk = (n + 1023) / 1024;
  const int lo = t * chunk;
  const int hi = min(lo + chunk, n);
  int s = 0;
  for (int i = lo; i < hi; ++i) s += counts[i];
  sums[t] = s;
  __syncthreads();
  // inclusive Hillis-Steele block scan
  for (int off = 1; off < 1024; off <<= 1) {
    int v = (t >= off) ? sums[t - off] : 0;
    __syncthreads();
    sums[t] += v;
    __syncthreads();
  }
  int prefix = (t == 0) ? 0 : sums[t - 1];
  for (int i = lo; i < hi; ++i) {
    offsets[i] = prefix;
    cursor[i] = prefix;
    prefix += counts[i];
  }
  if (t == 0) offsets[n] = sums[1023];
}

__global__ __launch_bounds__(256) void fill_csr(const int* __restrict__ erows,
                                                const int* __restrict__ ecols,
                                                const float* __restrict__ evals,
                                                int* __restrict__ cursor,
                                                int2* __restrict__ sedge,
                                                int n_edges) {
  int e = blockIdx.x * 256 + threadIdx.x;
  if (e < n_edges) {
    int r = erows[e];
    int pos = atomicAdd(&cursor[r], 1);
    int2 packed; packed.x = ecols[e]; packed.y = __float_as_int(evals[e]);
    sedge[pos] = packed;
  }
}

// ---------------- gather: out[node] = bias + sum val*h[col] ----------------
// One wave per node; lane l owns features 2l, 2l+1.
__global__ __launch_bounds__(256) void gather_nodes(
    const float* __restrict__ h, const int* __restrict__ offsets,
    const int2* __restrict__ sedge, const float* __restrict__ bias,
    float* __restrict__ out, int n_nodes) {
  int node = blockIdx.x * 4 + (threadIdx.x >> 6);
  if (node >= n_nodes) return;
  int lane = threadIdx.x & 63;
  float2 acc = ((const float2*)bias)[lane];
  int p = offsets[node];
  int p1 = offsets[node + 1];
  for (; p < p1; ++p) {
    int2 ev = sedge[p];                                       // wave-uniform 8B
    float v = __int_as_float(ev.y);
    float2 m = ((const float2*)(h + (size_t)ev.x * 128))[lane]; // coalesced 512B
    acc.x += v * m.x;
    acc.y += v * m.y;
  }
  ((float2*)(out + (size_t)node * 128))[lane] = acc;
}

// ---------------- fallback (small ws): atomic scatter ----------------
__global__ __launch_bounds__(256) void init_bias(float* __restrict__ out,
                                                 const float* __restrict__ bias,
                                                 int n4) {
  int i = blockIdx.x * 256 + threadIdx.x;
  if (i < n4) {
    float4 b = ((const float4*)bias)[i & 31];
    ((float4*)out)[i] = b;
  }
}

__global__ __launch_bounds__(256) void scatter_edges(
    const float* __restrict__ h, const int* __restrict__ erows,
    const int* __restrict__ ecols, const float* __restrict__ evals,
    float* __restrict__ out, int n_edges) {
  int e = blockIdx.x * 4 + (threadIdx.x >> 6);
  if (e >= n_edges) return;
  int lane = threadIdx.x & 63;
  int row = erows[e];
  int col = ecols[e];
  float v = evals[e];
  float2 m = ((const float2*)(h + (size_t)col * 128))[lane];
  float* op = out + (size_t)row * 128 + lane * 2;
  atomicAdd(op, v * m.x);
  atomicAdd(op + 1, v * m.y);
}

extern "C" void kernel_launch(void* const* d_in, const int* in_sizes, int n_in,
                              void* d_out, int out_size, void* d_ws, size_t ws_size,
                              hipStream_t stream) {
  const float* x     = (const float*)d_in[0];
  const int*   erows = (const int*)d_in[1];
  const int*   ecols = (const int*)d_in[2];
  const float* evals = (const float*)d_in[3];
  const float* w     = (const float*)d_in[4];
  const float* bias  = (const float*)d_in[5];
  float* out = (float*)d_out;

  const int n_nodes = in_sizes[0] / 256;
  const int n_edges = in_sizes[1];

  // ws carve-up (16B aligned)
  char* ws = (char*)d_ws;
  size_t off = 0;
  float* h = (float*)(ws + off);          off += (size_t)n_nodes * 128 * 4;
  int* counts  = (int*)(ws + off);        off += ((size_t)n_nodes * 4 + 15) & ~15ull;
  int* offsets = (int*)(ws + off);        off += ((size_t)(n_nodes + 1) * 4 + 15) & ~15ull;
  int* cursor  = (int*)(ws + off);        off += ((size_t)n_nodes * 4 + 15) & ~15ull;
  int2* sedge  = (int2*)(ws + off);       off += (size_t)n_edges * 8;
  const bool csr_ok = (off <= ws_size);

  const int gemm_blocks = (n_nodes + NODES_PER_BLOCK - 1) / NODES_PER_BLOCK;
  gemm_xw<<<gemm_blocks, 256, 0, stream>>>(x, w, h, n_nodes);

  if (csr_ok) {
    hipMemsetAsync(counts, 0, (size_t)n_nodes * 4, stream);
    hist_rows<<<(n_edges + 255) / 256, 256, 0, stream>>>(erows, counts, n_edges);
    scan_counts<<<1, 1024, 0, stream>>>(counts, offsets, cursor, n_nodes);
    fill_csr<<<(n_edges + 255) / 256, 256, 0, stream>>>(erows, ecols, evals,
                                                        cursor, sedge, n_edges);
    gather_nodes<<<(n_nodes + 3) / 4, 256, 0, stream>>>(h, offsets, sedge, bias,
                                                        out, n_nodes);
  } else {
    const int n4 = out_size / 4;
    init_bias<<<(n4 + 255) / 256, 256, 0, stream>>>(out, bias, n4);
    scatter_edges<<<(n_edges + 3) / 4, 256, 0, stream>>>(h, erows, ecols, evals,
                                                         out, n_edges);
  }
}

// Round 3
// 589.051 us; speedup vs baseline: 2.7109x; 1.4503x over previous
//
#include <hip/hip_runtime.h>

// GCNConv forward: out = segment_sum(vals * (x@W)[cols], rows) + bias
// Round 3: multi-block scan (was 228us single-block), gather unrolled x4.
//
// ws layout: h[N*128] f32 | counts[N] i32 | offsets[N+1] i32 | cursor[N] i32 |
//            sedge[E] int2 (col, val-bits) | bsum[128] | bpre[128]

#define NODES_PER_BLOCK 32
#define SCAN_CHUNK 1024   // counts per block in the 3-phase scan

// ---------------- GEMM: h = x @ W ----------------
__global__ __launch_bounds__(256) void gemm_xw(const float* __restrict__ x,
                                               const float* __restrict__ w,
                                               float* __restrict__ h,
                                               int n_nodes) {
  __shared__ float wt[64 * 128];   // wt[c*128 + f] = W[k0+c][f]
  __shared__ float xt[64 * 36];    // xt[c*36 + r] = x[row0+r][k0+c]
  const int t = threadIdx.x;
  const int fp = t & 63;
  const int rg = t >> 6;
  const int row0 = blockIdx.x * NODES_PER_BLOCK;

  float acc[8][2];
#pragma unroll
  for (int r = 0; r < 8; ++r) { acc[r][0] = 0.f; acc[r][1] = 0.f; }

  for (int kt = 0; kt < 4; ++kt) {
    const int k0 = kt * 64;
    const float4* wg = (const float4*)(w + k0 * 128);
    float4* wl = (float4*)wt;
#pragma unroll
    for (int i = 0; i < 8; ++i) wl[i * 256 + t] = wg[i * 256 + t];
#pragma unroll
    for (int i = 0; i < 8; ++i) {
      int idx = i * 256 + t;
      int r = idx >> 6, c = idx & 63;
      int row = row0 + r;
      xt[c * 36 + r] = (row < n_nodes) ? x[(size_t)row * 256 + k0 + c] : 0.f;
    }
    __syncthreads();
#pragma unroll 4
    for (int c = 0; c < 64; ++c) {
      const float2 wv = *(const float2*)&wt[c * 128 + fp * 2];
      const float4 xa = *(const float4*)&xt[c * 36 + rg * 8];
      const float4 xb = *(const float4*)&xt[c * 36 + rg * 8 + 4];
      acc[0][0] += xa.x * wv.x; acc[0][1] += xa.x * wv.y;
      acc[1][0] += xa.y * wv.x; acc[1][1] += xa.y * wv.y;
      acc[2][0] += xa.z * wv.x; acc[2][1] += xa.z * wv.y;
      acc[3][0] += xa.w * wv.x; acc[3][1] += xa.w * wv.y;
      acc[4][0] += xb.x * wv.x; acc[4][1] += xb.x * wv.y;
      acc[5][0] += xb.y * wv.x; acc[5][1] += xb.y * wv.y;
      acc[6][0] += xb.z * wv.x; acc[6][1] += xb.z * wv.y;
      acc[7][0] += xb.w * wv.x; acc[7][1] += xb.w * wv.y;
    }
    __syncthreads();
  }
#pragma unroll
  for (int r = 0; r < 8; ++r) {
    int row = row0 + rg * 8 + r;
    if (row < n_nodes) {
      float2 o; o.x = acc[r][0]; o.y = acc[r][1];
      *(float2*)&h[(size_t)row * 128 + fp * 2] = o;
    }
  }
}

// ---------------- CSR build ----------------
__global__ __launch_bounds__(256) void hist_rows(const int* __restrict__ erows,
                                                 int* __restrict__ counts,
                                                 int n_edges) {
  int i = blockIdx.x * 256 + threadIdx.x;
  if (i < n_edges) atomicAdd(&counts[erows[i]], 1);
}

// --- 3-phase scan: reduce chunks -> scan block sums -> write offsets ---
__global__ __launch_bounds__(256) void reduce_chunks(const int* __restrict__ counts,
                                                     int* __restrict__ bsum, int n) {
  const int b = blockIdx.x;
  const int t = threadIdx.x;
  const int base = b * SCAN_CHUNK + t * 4;
  int s = 0;
  if (base + 4 <= n) {
    int4 v = *(const int4*)&counts[base];
    s = v.x + v.y + v.z + v.w;
  } else {
    for (int i = base; i < n; ++i) s += counts[i];
  }
#pragma unroll
  for (int off = 32; off; off >>= 1) s += __shfl_down(s, off, 64);
  __shared__ int wsum[4];
  if ((t & 63) == 0) wsum[t >> 6] = s;
  __syncthreads();
  if (t == 0) bsum[b] = wsum[0] + wsum[1] + wsum[2] + wsum[3];
}

__global__ __launch_bounds__(128) void scan_bsums(const int* __restrict__ bsum,
                                                  int* __restrict__ bpre,
                                                  int* __restrict__ offsets,
                                                  int nb, int n) {
  __shared__ int s[128];
  const int t = threadIdx.x;
  int v = (t < nb) ? bsum[t] : 0;
  s[t] = v;
  __syncthreads();
  for (int off = 1; off < 128; off <<= 1) {
    int u = (t >= off) ? s[t - off] : 0;
    __syncthreads();
    s[t] += u;
    __syncthreads();
  }
  if (t < nb) bpre[t] = s[t] - v;      // exclusive prefix of block sums
  if (t == 0) offsets[n] = s[127];     // grand total
}

__global__ __launch_bounds__(256) void write_offsets(const int* __restrict__ counts,
                                                     const int* __restrict__ bpre,
                                                     int* __restrict__ offsets,
                                                     int* __restrict__ cursor, int n) {
  const int b = blockIdx.x;
  const int t = threadIdx.x;
  const int base = b * SCAN_CHUNK + t * 4;
  int c0 = 0, c1 = 0, c2 = 0, c3 = 0;
  if (base + 4 <= n) {
    int4 v = *(const int4*)&counts[base];
    c0 = v.x; c1 = v.y; c2 = v.z; c3 = v.w;
  } else {
    if (base + 0 < n) c0 = counts[base + 0];
    if (base + 1 < n) c1 = counts[base + 1];
    if (base + 2 < n) c2 = counts[base + 2];
    if (base + 3 < n) c3 = counts[base + 3];
  }
  const int mysum = c0 + c1 + c2 + c3;
  __shared__ int sums[256];
  sums[t] = mysum;
  __syncthreads();
  for (int off = 1; off < 256; off <<= 1) {
    int u = (t >= off) ? sums[t - off] : 0;
    __syncthreads();
    sums[t] += u;
    __syncthreads();
  }
  int pre = bpre[b] + sums[t] - mysum;   // exclusive prefix for this thread
  if (base + 0 < n) { offsets[base + 0] = pre; cursor[base + 0] = pre; pre += c0; }
  if (base + 1 < n) { offsets[base + 1] = pre; cursor[base + 1] = pre; pre += c1; }
  if (base + 2 < n) { offsets[base + 2] = pre; cursor[base + 2] = pre; pre += c2; }
  if (base + 3 < n) { offsets[base + 3] = pre; cursor[base + 3] = pre; pre += c3; }
}

// legacy single-block scan (fallback for n > 128*SCAN_CHUNK)
__global__ __launch_bounds__(1024) void scan_counts(const int* __restrict__ counts,
                                                    int* __restrict__ offsets,
                                                    int* __restrict__ cursor,
                                                    int n) {
  __shared__ int sums[1024];
  const int t = threadIdx.x;
  const int chunk = (n + 1023) / 1024;
  const int lo = t * chunk;
  const int hi = min(lo + chunk, n);
  int s = 0;
  for (int i = lo; i < hi; ++i) s += counts[i];
  sums[t] = s;
  __syncthreads();
  for (int off = 1; off < 1024; off <<= 1) {
    int v = (t >= off) ? sums[t - off] : 0;
    __syncthreads();
    sums[t] += v;
    __syncthreads();
  }
  int prefix = (t == 0) ? 0 : sums[t - 1];
  for (int i = lo; i < hi; ++i) {
    offsets[i] = prefix;
    cursor[i] = prefix;
    prefix += counts[i];
  }
  if (t == 0) offsets[n] = sums[1023];
}

__global__ __launch_bounds__(256) void fill_csr(const int* __restrict__ erows,
                                                const int* __restrict__ ecols,
                                                const float* __restrict__ evals,
                                                int* __restrict__ cursor,
                                                int2* __restrict__ sedge,
                                                int n_edges) {
  int e = blockIdx.x * 256 + threadIdx.x;
  if (e < n_edges) {
    int r = erows[e];
    int pos = atomicAdd(&cursor[r], 1);
    int2 packed; packed.x = ecols[e]; packed.y = __float_as_int(evals[e]);
    sedge[pos] = packed;
  }
}

// ---------------- gather: out[node] = bias + sum val*h[col] ----------------
// One wave per node; lane l owns features 2l, 2l+1. Unrolled x4 so four
// independent 512B h-gathers are in flight per wave.
__global__ __launch_bounds__(256) void gather_nodes(
    const float* __restrict__ h, const int* __restrict__ offsets,
    const int2* __restrict__ sedge, const float* __restrict__ bias,
    float* __restrict__ out, int n_nodes) {
  int node = blockIdx.x * 4 + (threadIdx.x >> 6);
  if (node >= n_nodes) return;
  int lane = threadIdx.x & 63;
  float2 acc = ((const float2*)bias)[lane];
  int p = offsets[node];
  const int p1 = offsets[node + 1];
  for (; p + 4 <= p1; p += 4) {
    int2 e0 = sedge[p + 0];
    int2 e1 = sedge[p + 1];
    int2 e2 = sedge[p + 2];
    int2 e3 = sedge[p + 3];
    float2 m0 = ((const float2*)(h + (size_t)e0.x * 128))[lane];
    float2 m1 = ((const float2*)(h + (size_t)e1.x * 128))[lane];
    float2 m2 = ((const float2*)(h + (size_t)e2.x * 128))[lane];
    float2 m3 = ((const float2*)(h + (size_t)e3.x * 128))[lane];
    float v0 = __int_as_float(e0.y), v1 = __int_as_float(e1.y);
    float v2 = __int_as_float(e2.y), v3 = __int_as_float(e3.y);
    acc.x += v0 * m0.x; acc.y += v0 * m0.y;
    acc.x += v1 * m1.x; acc.y += v1 * m1.y;
    acc.x += v2 * m2.x; acc.y += v2 * m2.y;
    acc.x += v3 * m3.x; acc.y += v3 * m3.y;
  }
  for (; p < p1; ++p) {
    int2 ev = sedge[p];
    float v = __int_as_float(ev.y);
    float2 m = ((const float2*)(h + (size_t)ev.x * 128))[lane];
    acc.x += v * m.x;
    acc.y += v * m.y;
  }
  ((float2*)(out + (size_t)node * 128))[lane] = acc;
}

// ---------------- fallback (small ws): atomic scatter ----------------
__global__ __launch_bounds__(256) void init_bias(float* __restrict__ out,
                                                 const float* __restrict__ bias,
                                                 int n4) {
  int i = blockIdx.x * 256 + threadIdx.x;
  if (i < n4) {
    float4 b = ((const float4*)bias)[i & 31];
    ((float4*)out)[i] = b;
  }
}

__global__ __launch_bounds__(256) void scatter_edges(
    const float* __restrict__ h, const int* __restrict__ erows,
    const int* __restrict__ ecols, const float* __restrict__ evals,
    float* __restrict__ out, int n_edges) {
  int e = blockIdx.x * 4 + (threadIdx.x >> 6);
  if (e >= n_edges) return;
  int lane = threadIdx.x & 63;
  int row = erows[e];
  int col = ecols[e];
  float v = evals[e];
  float2 m = ((const float2*)(h + (size_t)col * 128))[lane];
  float* op = out + (size_t)row * 128 + lane * 2;
  atomicAdd(op, v * m.x);
  atomicAdd(op + 1, v * m.y);
}

extern "C" void kernel_launch(void* const* d_in, const int* in_sizes, int n_in,
                              void* d_out, int out_size, void* d_ws, size_t ws_size,
                              hipStream_t stream) {
  const float* x     = (const float*)d_in[0];
  const int*   erows = (const int*)d_in[1];
  const int*   ecols = (const int*)d_in[2];
  const float* evals = (const float*)d_in[3];
  const float* w     = (const float*)d_in[4];
  const float* bias  = (const float*)d_in[5];
  float* out = (float*)d_out;

  const int n_nodes = in_sizes[0] / 256;
  const int n_edges = in_sizes[1];

  // ws carve-up (16B aligned)
  char* ws = (char*)d_ws;
  size_t off = 0;
  float* h = (float*)(ws + off);          off += (size_t)n_nodes * 128 * 4;
  int* counts  = (int*)(ws + off);        off += ((size_t)n_nodes * 4 + 15) & ~15ull;
  int* offsets = (int*)(ws + off);        off += ((size_t)(n_nodes + 1) * 4 + 15) & ~15ull;
  int* cursor  = (int*)(ws + off);        off += ((size_t)n_nodes * 4 + 15) & ~15ull;
  int2* sedge  = (int2*)(ws + off);       off += (size_t)n_edges * 8;
  int* bsum    = (int*)(ws + off);        off += 128 * 4;
  int* bpre    = (int*)(ws + off);        off += 128 * 4;
  const bool csr_ok = (off <= ws_size);

  const int gemm_blocks = (n_nodes + NODES_PER_BLOCK - 1) / NODES_PER_BLOCK;
  gemm_xw<<<gemm_blocks, 256, 0, stream>>>(x, w, h, n_nodes);

  if (csr_ok) {
    hipMemsetAsync(counts, 0, (size_t)n_nodes * 4, stream);
    hist_rows<<<(n_edges + 255) / 256, 256, 0, stream>>>(erows, counts, n_edges);
    const int nb = (n_nodes + SCAN_CHUNK - 1) / SCAN_CHUNK;
    if (nb <= 128) {
      reduce_chunks<<<nb, 256, 0, stream>>>(counts, bsum, n_nodes);
      scan_bsums<<<1, 128, 0, stream>>>(bsum, bpre, offsets, nb, n_nodes);
      write_offsets<<<nb, 256, 0, stream>>>(counts, bpre, offsets, cursor, n_nodes);
    } else {
      scan_counts<<<1, 1024, 0, stream>>>(counts, offsets, cursor, n_nodes);
    }
    fill_csr<<<(n_edges + 255) / 256, 256, 0, stream>>>(erows, ecols, evals,
                                                        cursor, sedge, n_edges);
    gather_nodes<<<(n_nodes + 3) / 4, 256, 0, stream>>>(h, offsets, sedge, bias,
                                                        out, n_nodes);
  } else {
    const int n4 = out_size / 4;
    init_bias<<<(n4 + 255) / 256, 256, 0, stream>>>(out, bias, n4);
    scatter_edges<<<(n_edges + 3) / 4, 256, 0, stream>>>(h, erows, ecols, evals,
                                                         out, n_edges);
  }
}

// Round 4
// 452.800 us; speedup vs baseline: 3.5267x; 1.3009x over previous
//
#include <hip/hip_runtime.h>

// GCNConv forward: out = segment_sum(vals * (x@W)[cols], rows) + bias
// Round 4: GEMM -> bf16 MFMA (h^T = W^T x^T formulation, W resident in LDS),
// h stored as bf16 (halves gather traffic). CSR machinery unchanged.
//
// ws layout: h[N*128] bf16 | wt[128*264] bf16 | counts[N] i32 | offsets[N+1] |
//            cursor[N] | sedge[E] int2 | bsum[128] | bpre[128]

typedef __attribute__((ext_vector_type(8))) short short8;
typedef __attribute__((ext_vector_type(4))) float floatx4;

#define WT_K 264          // padded k extent of wt (bf16 elems), 264*2=528B rows
#define GM_NODES 128      // nodes per GEMM block
#define SCAN_CHUNK 1024

static __device__ __forceinline__ uint f2bf(float x) {  // RNE f32->bf16 bits
  uint u = __float_as_uint(x);
  return (u + 0x7fffu + ((u >> 16) & 1u)) >> 16;
}

// ---- W[k][f] f32  ->  wt[f][k] bf16 (k padded to WT_K) ----
__global__ __launch_bounds__(256) void conv_w(const float* __restrict__ w,
                                              ushort* __restrict__ wt) {
  const int f = blockIdx.x;    // 128
  const int k = threadIdx.x;   // 256
  wt[f * WT_K + k] = (ushort)f2bf(w[k * 128 + f]);
}

// ---- GEMM: h[node][f] = sum_k x[node][k] W[k][f], computed as h^T = W^T x^T.
// A-op = wt[f][k] (m=f), B-op = x^T (n=node). D: lane holds 4 consecutive f
// (quad*4+reg) for node = n0 + (lane&15)  ->  one 8B bf16x4 store per tile.
__global__ __launch_bounds__(256) void gemm_mfma(const float* __restrict__ x,
                                                 const ushort* __restrict__ wt,
                                                 ushort* __restrict__ h,
                                                 int n_nodes) {
  __shared__ ushort lw[128 * WT_K];      // 67584 B
  __shared__ ushort xa[GM_NODES * 40];   // [node][k(32)+pad8] bf16, 10240 B
  const int t = threadIdx.x;
  const int lane = t & 63;
  const int wq = t >> 6;
  const int quad = lane >> 4;
  const int l15 = lane & 15;
  const int row0 = blockIdx.x * GM_NODES;

  // wt -> LDS (4224 x 16B, coalesced)
  {
    const uint4* src = (const uint4*)wt;
    uint4* dst = (uint4*)lw;
    for (int i = t; i < (128 * WT_K * 2) / 16; i += 256) dst[i] = src[i];
  }

  floatx4 acc[2][8];
#pragma unroll
  for (int nt = 0; nt < 2; ++nt)
#pragma unroll
    for (int mt = 0; mt < 8; ++mt) acc[nt][mt] = (floatx4){0.f, 0.f, 0.f, 0.f};

  // staging: 128 rows x 32 k fp32 = 1024 float4, 4 per thread
  float4 cur[4];
#pragma unroll
  for (int i = 0; i < 4; ++i) {
    const int idx = i * 256 + t;
    const int row = idx >> 3, kq = idx & 7;
    const int gr = row0 + row;
    cur[i] = (gr < n_nodes) ? *(const float4*)&x[(size_t)gr * 256 + kq * 4]
                            : make_float4(0.f, 0.f, 0.f, 0.f);
  }

  for (int kc = 0; kc < 8; ++kc) {
    // cur -> xa (bf16 pack, 8B per thread-iter)
#pragma unroll
    for (int i = 0; i < 4; ++i) {
      const int idx = i * 256 + t;
      const int row = idx >> 3, kq = idx & 7;
      uint2 p;
      p.x = f2bf(cur[i].x) | (f2bf(cur[i].y) << 16);
      p.y = f2bf(cur[i].z) | (f2bf(cur[i].w) << 16);
      *(uint2*)&xa[row * 40 + kq * 4] = p;
    }
    __syncthreads();

    float4 nxt[4];
    if (kc < 7) {
#pragma unroll
      for (int i = 0; i < 4; ++i) {
        const int idx = i * 256 + t;
        const int row = idx >> 3, kq = idx & 7;
        const int gr = row0 + row;
        nxt[i] = (gr < n_nodes)
                     ? *(const float4*)&x[(size_t)gr * 256 + (kc + 1) * 32 + kq * 4]
                     : make_float4(0.f, 0.f, 0.f, 0.f);
      }
    }

    short8 bfr[2];
    bfr[0] = *(const short8*)&xa[(wq * 32 + l15) * 40 + quad * 8];
    bfr[1] = *(const short8*)&xa[(wq * 32 + 16 + l15) * 40 + quad * 8];
#pragma unroll
    for (int mt = 0; mt < 8; ++mt) {
      const short8 afr =
          *(const short8*)&lw[(mt * 16 + l15) * WT_K + kc * 32 + quad * 8];
      acc[0][mt] = __builtin_amdgcn_mfma_f32_16x16x32_bf16(afr, bfr[0],
                                                           acc[0][mt], 0, 0, 0);
      acc[1][mt] = __builtin_amdgcn_mfma_f32_16x16x32_bf16(afr, bfr[1],
                                                           acc[1][mt], 0, 0, 0);
    }
    __syncthreads();
#pragma unroll
    for (int i = 0; i < 4; ++i) cur[i] = nxt[i];
  }

  // epilogue: lane holds f = mt*16 + quad*4 + {0..3} for its node
#pragma unroll
  for (int nt = 0; nt < 2; ++nt) {
    const int node = row0 + wq * 32 + nt * 16 + l15;
    if (node < n_nodes) {
#pragma unroll
      for (int mt = 0; mt < 8; ++mt) {
        uint2 p;
        p.x = f2bf(acc[nt][mt][0]) | (f2bf(acc[nt][mt][1]) << 16);
        p.y = f2bf(acc[nt][mt][2]) | (f2bf(acc[nt][mt][3]) << 16);
        *(uint2*)&h[(size_t)node * 128 + mt * 16 + quad * 4] = p;
      }
    }
  }
}

// ---------------- CSR build ----------------
__global__ __launch_bounds__(256) void hist_rows(const int* __restrict__ erows,
                                                 int* __restrict__ counts,
                                                 int n_edges) {
  int i = blockIdx.x * 256 + threadIdx.x;
  if (i < n_edges) atomicAdd(&counts[erows[i]], 1);
}

__global__ __launch_bounds__(256) void reduce_chunks(const int* __restrict__ counts,
                                                     int* __restrict__ bsum, int n) {
  const int b = blockIdx.x;
  const int t = threadIdx.x;
  const int base = b * SCAN_CHUNK + t * 4;
  int s = 0;
  if (base + 4 <= n) {
    int4 v = *(const int4*)&counts[base];
    s = v.x + v.y + v.z + v.w;
  } else {
    for (int i = base; i < n; ++i) s += counts[i];
  }
#pragma unroll
  for (int off = 32; off; off >>= 1) s += __shfl_down(s, off, 64);
  __shared__ int wsum[4];
  if ((t & 63) == 0) wsum[t >> 6] = s;
  __syncthreads();
  if (t == 0) bsum[b] = wsum[0] + wsum[1] + wsum[2] + wsum[3];
}

__global__ __launch_bounds__(128) void scan_bsums(const int* __restrict__ bsum,
                                                  int* __restrict__ bpre,
                                                  int* __restrict__ offsets,
                                                  int nb, int n) {
  __shared__ int s[128];
  const int t = threadIdx.x;
  int v = (t < nb) ? bsum[t] : 0;
  s[t] = v;
  __syncthreads();
  for (int off = 1; off < 128; off <<= 1) {
    int u = (t >= off) ? s[t - off] : 0;
    __syncthreads();
    s[t] += u;
    __syncthreads();
  }
  if (t < nb) bpre[t] = s[t] - v;
  if (t == 0) offsets[n] = s[127];
}

__global__ __launch_bounds__(256) void write_offsets(const int* __restrict__ counts,
                                                     const int* __restrict__ bpre,
                                                     int* __restrict__ offsets,
                                                     int* __restrict__ cursor, int n) {
  const int b = blockIdx.x;
  const int t = threadIdx.x;
  const int base = b * SCAN_CHUNK + t * 4;
  int c0 = 0, c1 = 0, c2 = 0, c3 = 0;
  if (base + 4 <= n) {
    int4 v = *(const int4*)&counts[base];
    c0 = v.x; c1 = v.y; c2 = v.z; c3 = v.w;
  } else {
    if (base + 0 < n) c0 = counts[base + 0];
    if (base + 1 < n) c1 = counts[base + 1];
    if (base + 2 < n) c2 = counts[base + 2];
    if (base + 3 < n) c3 = counts[base + 3];
  }
  const int mysum = c0 + c1 + c2 + c3;
  __shared__ int sums[256];
  sums[t] = mysum;
  __syncthreads();
  for (int off = 1; off < 256; off <<= 1) {
    int u = (t >= off) ? sums[t - off] : 0;
    __syncthreads();
    sums[t] += u;
    __syncthreads();
  }
  int pre = bpre[b] + sums[t] - mysum;
  if (base + 0 < n) { offsets[base + 0] = pre; cursor[base + 0] = pre; pre += c0; }
  if (base + 1 < n) { offsets[base + 1] = pre; cursor[base + 1] = pre; pre += c1; }
  if (base + 2 < n) { offsets[base + 2] = pre; cursor[base + 2] = pre; pre += c2; }
  if (base + 3 < n) { offsets[base + 3] = pre; cursor[base + 3] = pre; pre += c3; }
}

__global__ __launch_bounds__(256) void fill_csr(const int* __restrict__ erows,
                                                const int* __restrict__ ecols,
                                                const float* __restrict__ evals,
                                                int* __restrict__ cursor,
                                                int2* __restrict__ sedge,
                                                int n_edges) {
  int e = blockIdx.x * 256 + threadIdx.x;
  if (e < n_edges) {
    int r = erows[e];
    int pos = atomicAdd(&cursor[r], 1);
    int2 packed; packed.x = ecols[e]; packed.y = __float_as_int(evals[e]);
    sedge[pos] = packed;
  }
}

// ---- gather: out[node] = bias + sum val * h_bf16[col]; lane = feats 2l,2l+1 ----
__global__ __launch_bounds__(256) void gather_nodes(
    const ushort* __restrict__ h, const int* __restrict__ offsets,
    const int2* __restrict__ sedge, const float* __restrict__ bias,
    float* __restrict__ out, int n_nodes) {
  int node = blockIdx.x * 4 + (threadIdx.x >> 6);
  if (node >= n_nodes) return;
  int lane = threadIdx.x & 63;
  float2 acc = ((const float2*)bias)[lane];
  int p = offsets[node];
  const int p1 = offsets[node + 1];
  for (; p + 4 <= p1; p += 4) {
    int2 e0 = sedge[p + 0];
    int2 e1 = sedge[p + 1];
    int2 e2 = sedge[p + 2];
    int2 e3 = sedge[p + 3];
    uint u0 = ((const uint*)(h + (size_t)e0.x * 128))[lane];
    uint u1 = ((const uint*)(h + (size_t)e1.x * 128))[lane];
    uint u2 = ((const uint*)(h + (size_t)e2.x * 128))[lane];
    uint u3 = ((const uint*)(h + (size_t)e3.x * 128))[lane];
    float v0 = __int_as_float(e0.y), v1 = __int_as_float(e1.y);
    float v2 = __int_as_float(e2.y), v3 = __int_as_float(e3.y);
    acc.x += v0 * __uint_as_float(u0 << 16);
    acc.y += v0 * __uint_as_float(u0 & 0xffff0000u);
    acc.x += v1 * __uint_as_float(u1 << 16);
    acc.y += v1 * __uint_as_float(u1 & 0xffff0000u);
    acc.x += v2 * __uint_as_float(u2 << 16);
    acc.y += v2 * __uint_as_float(u2 & 0xffff0000u);
    acc.x += v3 * __uint_as_float(u3 << 16);
    acc.y += v3 * __uint_as_float(u3 & 0xffff0000u);
  }
  for (; p < p1; ++p) {
    int2 ev = sedge[p];
    float v = __int_as_float(ev.y);
    uint u = ((const uint*)(h + (size_t)ev.x * 128))[lane];
    acc.x += v * __uint_as_float(u << 16);
    acc.y += v * __uint_as_float(u & 0xffff0000u);
  }
  ((float2*)(out + (size_t)node * 128))[lane] = acc;
}

// ---- fallback (small ws): bias init + atomic scatter on bf16 h ----
__global__ __launch_bounds__(256) void init_bias(float* __restrict__ out,
                                                 const float* __restrict__ bias,
                                                 int n4) {
  int i = blockIdx.x * 256 + threadIdx.x;
  if (i < n4) {
    float4 b = ((const float4*)bias)[i & 31];
    ((float4*)out)[i] = b;
  }
}

__global__ __launch_bounds__(256) void scatter_edges(
    const ushort* __restrict__ h, const int* __restrict__ erows,
    const int* __restrict__ ecols, const float* __restrict__ evals,
    float* __restrict__ out, int n_edges) {
  int e = blockIdx.x * 4 + (threadIdx.x >> 6);
  if (e >= n_edges) return;
  int lane = threadIdx.x & 63;
  int row = erows[e];
  int col = ecols[e];
  float v = evals[e];
  uint u = ((const uint*)(h + (size_t)col * 128))[lane];
  float* op = out + (size_t)row * 128 + lane * 2;
  atomicAdd(op, v * __uint_as_float(u << 16));
  atomicAdd(op + 1, v * __uint_as_float(u & 0xffff0000u));
}

extern "C" void kernel_launch(void* const* d_in, const int* in_sizes, int n_in,
                              void* d_out, int out_size, void* d_ws, size_t ws_size,
                              hipStream_t stream) {
  const float* x     = (const float*)d_in[0];
  const int*   erows = (const int*)d_in[1];
  const int*   ecols = (const int*)d_in[2];
  const float* evals = (const float*)d_in[3];
  const float* w     = (const float*)d_in[4];
  const float* bias  = (const float*)d_in[5];
  float* out = (float*)d_out;

  const int n_nodes = in_sizes[0] / 256;
  const int n_edges = in_sizes[1];

  // ws carve-up (16B aligned)
  char* ws = (char*)d_ws;
  size_t off = 0;
  ushort* h  = (ushort*)(ws + off);  off += ((size_t)n_nodes * 128 * 2 + 15) & ~15ull;
  ushort* wt = (ushort*)(ws + off);  off += ((size_t)128 * WT_K * 2 + 15) & ~15ull;
  int* counts  = (int*)(ws + off);   off += ((size_t)n_nodes * 4 + 15) & ~15ull;
  int* offsets = (int*)(ws + off);   off += ((size_t)(n_nodes + 1) * 4 + 15) & ~15ull;
  int* cursor  = (int*)(ws + off);   off += ((size_t)n_nodes * 4 + 15) & ~15ull;
  int2* sedge  = (int2*)(ws + off);  off += (size_t)n_edges * 8;
  int* bsum    = (int*)(ws + off);   off += 128 * 4;
  int* bpre    = (int*)(ws + off);   off += 128 * 4;
  const bool csr_ok = (off <= ws_size);

  conv_w<<<128, 256, 0, stream>>>(w, wt);
  const int gemm_blocks = (n_nodes + GM_NODES - 1) / GM_NODES;
  gemm_mfma<<<gemm_blocks, 256, 0, stream>>>(x, wt, h, n_nodes);

  if (csr_ok) {
    hipMemsetAsync(counts, 0, (size_t)n_nodes * 4, stream);
    hist_rows<<<(n_edges + 255) / 256, 256, 0, stream>>>(erows, counts, n_edges);
    const int nb = (n_nodes + SCAN_CHUNK - 1) / SCAN_CHUNK;
    reduce_chunks<<<nb, 256, 0, stream>>>(counts, bsum, n_nodes);
    scan_bsums<<<1, 128, 0, stream>>>(bsum, bpre, offsets, nb, n_nodes);
    write_offsets<<<nb, 256, 0, stream>>>(counts, bpre, offsets, cursor, n_nodes);
    fill_csr<<<(n_edges + 255) / 256, 256, 0, stream>>>(erows, ecols, evals,
                                                        cursor, sedge, n_edges);
    gather_nodes<<<(n_nodes + 3) / 4, 256, 0, stream>>>(h, offsets, sedge, bias,
                                                        out, n_nodes);
  } else {
    const int n4 = out_size / 4;
    init_bias<<<(n4 + 255) / 256, 256, 0, stream>>>(out, bias, n4);
    scatter_edges<<<(n_edges + 3) / 4, 256, 0, stream>>>(h, erows, ecols, evals,
                                                         out, n_edges);
  }
}